// Round 1
// baseline (389.570 us; speedup 1.0000x reference)
//
#include <hip/hip_runtime.h>

typedef __attribute__((ext_vector_type(8))) short short8;
typedef __attribute__((ext_vector_type(4))) float f32x4;
typedef unsigned short u16;

#define T_SEQ 2048
#define C_DIM 2048
#define QKV_LD 6144

static __device__ __forceinline__ u16 f2bf(float f){
  unsigned u = __float_as_uint(f);
  u = (u + 0x7fffu + ((u >> 16) & 1u)) >> 16;
  return (u16)u;
}

__global__ void cvt_kernel(const float* __restrict__ in, u16* __restrict__ out, int n4){
  int idx = blockIdx.x * blockDim.x + threadIdx.x;
  int stride = gridDim.x * blockDim.x;
  for (int i = idx; i < n4; i += stride){
    float4 v = ((const float4*)in)[i];
    ushort4 o;
    o.x = f2bf(v.x); o.y = f2bf(v.y); o.z = f2bf(v.z); o.w = f2bf(v.w);
    ((ushort4*)out)[i] = o;
  }
}

__device__ __forceinline__ void gl_lds16(const void* g, void* l){
  __builtin_amdgcn_global_load_lds(
      (const __attribute__((address_space(1))) unsigned int*)g,
      (__attribute__((address_space(3))) unsigned int*)l,
      16, 0, 0);
}

// C[M,N] = A[M,K] * B[N,K]^T ; A,B bf16 row-major; OUT = bf16(u16) or f32.
template<typename OUT>
__global__ __launch_bounds__(256) void gemm_bt(const u16* __restrict__ A,
                                               const u16* __restrict__ B,
                                               OUT* __restrict__ C,
                                               int M, int N, int K){
  __shared__ __align__(16) u16 lA[2][128*32];
  __shared__ __align__(16) u16 lB[2][128*32];
  const int tid  = threadIdx.x;
  const int lane = tid & 63;
  const int r16  = lane & 15;
  const int g4   = lane >> 4;
  const int wave = tid >> 6;
  const int wr = (wave >> 1) * 64, wc = (wave & 1) * 64;
  const int m0 = blockIdx.y * 128, n0 = blockIdx.x * 128;
  const int srow = tid >> 2;          // 0..63
  const int scol = (tid & 3) << 3;    // 0,8,16,24

  f32x4 acc[4][4] = {};

  const int nk = K >> 5;
  int buf = 0;

  // stage K-tile 0
  gl_lds16(&A[(size_t)(m0 + srow)*K + scol],      &lA[0][srow*32 + scol]);
  gl_lds16(&A[(size_t)(m0 + 64 + srow)*K + scol], &lA[0][(64+srow)*32 + scol]);
  gl_lds16(&B[(size_t)(n0 + srow)*K + scol],      &lB[0][srow*32 + scol]);
  gl_lds16(&B[(size_t)(n0 + 64 + srow)*K + scol], &lB[0][(64+srow)*32 + scol]);

  for (int kt = 0; kt < nk; ++kt){
    __syncthreads();   // compiler drains vmcnt/lgkmcnt before s_barrier
    if (kt + 1 < nk){
      const int k0 = (kt + 1) << 5;
      gl_lds16(&A[(size_t)(m0 + srow)*K + k0 + scol],      &lA[buf^1][srow*32 + scol]);
      gl_lds16(&A[(size_t)(m0 + 64 + srow)*K + k0 + scol], &lA[buf^1][(64+srow)*32 + scol]);
      gl_lds16(&B[(size_t)(n0 + srow)*K + k0 + scol],      &lB[buf^1][srow*32 + scol]);
      gl_lds16(&B[(size_t)(n0 + 64 + srow)*K + k0 + scol], &lB[buf^1][(64+srow)*32 + scol]);
    }
    short8 af[4], bfv[4];
    #pragma unroll
    for (int i=0;i<4;i++)
      af[i] = *(const short8*)&lA[buf][(wr + i*16 + r16)*32 + g4*8];
    #pragma unroll
    for (int j=0;j<4;j++)
      bfv[j] = *(const short8*)&lB[buf][(wc + j*16 + r16)*32 + g4*8];
    #pragma unroll
    for (int i=0;i<4;i++)
      #pragma unroll
      for (int j=0;j<4;j++)
        acc[i][j] = __builtin_amdgcn_mfma_f32_16x16x32_bf16(af[i], bfv[j], acc[i][j], 0,0,0);
    buf ^= 1;
  }

  #pragma unroll
  for (int i=0;i<4;i++){
    const int row = m0 + wr + i*16 + g4*4;
    #pragma unroll
    for (int j=0;j<4;j++){
      const int col = n0 + wc + j*16 + r16;
      #pragma unroll
      for (int r=0;r<4;r++){
        float v = acc[i][j][r];
        if constexpr (sizeof(OUT)==2) C[(size_t)(row+r)*N + col] = (OUT)f2bf(v);
        else                          C[(size_t)(row+r)*N + col] = (OUT)v;
      }
    }
  }
}

// Flash attention: grid (T/64, B*NH); 4 waves, each owns 16 q-rows.
__global__ __launch_bounds__(256) void attn_kernel(const u16* __restrict__ qkv,
                                                   u16* __restrict__ y){
  __shared__ __align__(16) u16 Kl[64*128];     // [kv][d], XOR-swizzled
  __shared__ __align__(16) u16 Vt[128*64];     // [d][kv], XOR-swizzled
  __shared__ __align__(16) u16 Pl[4][16*64];   // per-wave P, XOR-swizzled

  const int tid = threadIdx.x, lane = tid & 63, wave = tid >> 6;
  const int r16 = lane & 15, g4 = lane >> 4;
  const int qt = blockIdx.x;
  const int bh = blockIdx.y;
  const int b = bh >> 4, h = bh & 15;
  const size_t base = (size_t)b * T_SEQ * QKV_LD;
  const int qcol = h*128, kcol = 2048 + h*128, vcol = 4096 + h*128;
  const float scale = 0.08838834764831845f;  // 1/sqrt(128)

  short8 qf[4];
  {
    const u16* qp = qkv + base + (size_t)(qt*64 + wave*16 + r16)*QKV_LD + qcol;
    #pragma unroll
    for (int c=0;c<4;c++) qf[c] = *(const short8*)&qp[g4*8 + c*32];
  }

  float mrow[4], lrow[4];
  #pragma unroll
  for (int r=0;r<4;r++){ mrow[r] = -1e30f; lrow[r] = 0.f; }
  f32x4 o[8] = {};

  const int strow = tid >> 4;          // 0..15
  const int stcol = (tid & 15) << 3;   // 0..120

  for (int t = 0; t <= qt; ++t){
    __syncthreads();   // previous tile's LDS reads all drained
    const size_t krow0 = base + (size_t)t*64*QKV_LD;
    // ---- stage K tile [64][128], swizzled, b128 writes
    #pragma unroll
    for (int r=0;r<4;r++){
      const int row = r*16 + strow;
      short8 kk = *(const short8*)&qkv[krow0 + (size_t)row*QKV_LD + kcol + stcol];
      *(short8*)&Kl[row*128 + (stcol ^ ((row&7)<<3))] = kk;
    }
    // ---- stage V transposed: lane owns kv=lane; per-instr writes are row-contiguous
    #pragma unroll
    for (int r=0;r<4;r++){
      const int d0 = wave*8 + r*32;
      short8 vv = *(const short8*)&qkv[krow0 + (size_t)lane*QKV_LD + vcol + d0];
      #pragma unroll
      for (int j=0;j<8;j++){
        const int d = d0 + j;
        Vt[d*64 + (lane ^ ((d&7)<<3))] = (u16)vv[j];
      }
    }
    __syncthreads();

    // ---- S = Q K^T (16q x 64kv per wave)
    float smat[4][4];
    #pragma unroll
    for (int cc=0;cc<4;cc++){
      const int krow = cc*16 + r16;
      const int sw = (krow & 7) << 3;
      f32x4 sv = {0.f,0.f,0.f,0.f};
      #pragma unroll
      for (int dc=0;dc<4;dc++){
        short8 kf = *(const short8*)&Kl[krow*128 + ((g4*8 + dc*32) ^ sw)];
        sv = __builtin_amdgcn_mfma_f32_16x16x32_bf16(qf[dc], kf, sv, 0,0,0);
      }
      #pragma unroll
      for (int rr=0;rr<4;rr++) smat[cc][rr] = sv[rr] * scale;
    }
    if (t == qt){  // only diagonal tile needs the causal mask (uniform branch)
      #pragma unroll
      for (int cc=0;cc<4;cc++){
        const int kvi = cc*16 + r16;
        #pragma unroll
        for (int rr=0;rr<4;rr++){
          const int qi = wave*16 + g4*4 + rr;
          if (kvi > qi) smat[cc][rr] = -1e30f;
        }
      }
    }

    // ---- online softmax (rows live on 16-lane groups; butterfly shfl)
    float corr[4];
    #pragma unroll
    for (int rr=0;rr<4;rr++){
      float pm = fmaxf(fmaxf(smat[0][rr], smat[1][rr]), fmaxf(smat[2][rr], smat[3][rr]));
      #pragma unroll
      for (int off=1; off<16; off<<=1) pm = fmaxf(pm, __shfl_xor(pm, off, 64));
      const float mnew = fmaxf(mrow[rr], pm);
      corr[rr] = __expf(mrow[rr] - mnew);
      float s0 = 0.f;
      #pragma unroll
      for (int cc=0;cc<4;cc++){
        const float p = __expf(smat[cc][rr] - mnew);
        smat[cc][rr] = p;
        s0 += p;
      }
      #pragma unroll
      for (int off=1; off<16; off<<=1) s0 += __shfl_xor(s0, off, 64);
      lrow[rr] = lrow[rr]*corr[rr] + s0;
      mrow[rr] = mnew;
    }
    #pragma unroll
    for (int n=0;n<8;n++)
      #pragma unroll
      for (int rr=0;rr<4;rr++)
        o[n][rr] *= corr[rr];

    // ---- P -> LDS (bf16), then PV
    #pragma unroll
    for (int cc=0;cc<4;cc++)
      #pragma unroll
      for (int rr=0;rr<4;rr++){
        const int qr = g4*4 + rr;
        Pl[wave][qr*64 + ((cc*16 + r16) ^ ((qr&7)<<3))] = f2bf(smat[cc][rr]);
      }
    asm volatile("s_waitcnt lgkmcnt(0)" ::: "memory");

    short8 pf0 = *(const short8*)&Pl[wave][r16*64 + ((g4*8)      ^ ((r16&7)<<3))];
    short8 pf1 = *(const short8*)&Pl[wave][r16*64 + ((g4*8 + 32) ^ ((r16&7)<<3))];
    #pragma unroll
    for (int n=0;n<8;n++){
      const int vr = n*16 + r16;
      const int sw = (vr & 7) << 3;
      short8 vf0 = *(const short8*)&Vt[vr*64 + ((g4*8)      ^ sw)];
      short8 vf1 = *(const short8*)&Vt[vr*64 + ((g4*8 + 32) ^ sw)];
      o[n] = __builtin_amdgcn_mfma_f32_16x16x32_bf16(pf0, vf0, o[n], 0,0,0);
      o[n] = __builtin_amdgcn_mfma_f32_16x16x32_bf16(pf1, vf1, o[n], 0,0,0);
    }
  }

  const size_t yr0 = (size_t)(b*T_SEQ + qt*64 + wave*16 + g4*4) * C_DIM + h*128;
  #pragma unroll
  for (int n=0;n<8;n++)
    #pragma unroll
    for (int rr=0;rr<4;rr++){
      const float v = o[n][rr] / lrow[rr];
      y[yr0 + (size_t)rr*C_DIM + n*16 + r16] = f2bf(v);
    }
}

extern "C" void kernel_launch(void* const* d_in, const int* in_sizes, int n_in,
                              void* d_out, int out_size, void* d_ws, size_t ws_size,
                              hipStream_t stream){
  const float* x  = (const float*)d_in[0];
  const float* wa = (const float*)d_in[1];
  const float* wp = (const float*)d_in[2];
  float* out = (float*)d_out;

  u16* ws  = (u16*)d_ws;
  u16* xb  = ws;                 //  8388608 elems (x bf16) — reused as yb later
  u16* wab = xb  + 8388608;      // 12582912 elems (w_attn bf16)
  u16* wpb = wab + 12582912;     //  4194304 elems (w_proj bf16)
  u16* qkv = wpb + 4194304;      // 25165824 elems (qkv bf16)
  u16* yb  = xb;                 // alias: x no longer needed after GEMM1

  hipLaunchKernelGGL(cvt_kernel, dim3(1024), dim3(256), 0, stream, x,  xb,  8388608/4);
  hipLaunchKernelGGL(cvt_kernel, dim3(1024), dim3(256), 0, stream, wa, wab, 12582912/4);
  hipLaunchKernelGGL(cvt_kernel, dim3(1024), dim3(256), 0, stream, wp, wpb, 4194304/4);

  // qkv[4096,6144] = xb[4096,2048] @ wab[6144,2048]^T
  hipLaunchKernelGGL((gemm_bt<u16>),   dim3(48,32), dim3(256), 0, stream,
                     xb, wab, qkv, 4096, 6144, 2048);
  // flash attention -> yb[4096,2048] bf16
  hipLaunchKernelGGL(attn_kernel,      dim3(32,32), dim3(256), 0, stream, qkv, yb);
  // out[4096,2048] f32 = yb @ wpb^T
  hipLaunchKernelGGL((gemm_bt<float>), dim3(16,32), dim3(256), 0, stream,
                     yb, wpb, out, 4096, 2048, 2048);
}

// Round 3
// 324.860 us; speedup vs baseline: 1.1992x; 1.1992x over previous
//
#include <hip/hip_runtime.h>

typedef __attribute__((ext_vector_type(8))) short short8;
typedef __attribute__((ext_vector_type(4))) float f32x4;
typedef unsigned short u16;

#define T_SEQ 2048
#define C_DIM 2048
#define QKV_LD 6144

static __device__ __forceinline__ u16 f2bf(float f){
  unsigned u = __float_as_uint(f);
  u = (u + 0x7fffu + ((u >> 16) & 1u)) >> 16;
  return (u16)u;
}

__global__ void cvt_kernel(const float* __restrict__ in, u16* __restrict__ out, int n4){
  int idx = blockIdx.x * blockDim.x + threadIdx.x;
  int stride = gridDim.x * blockDim.x;
  for (int i = idx; i < n4; i += stride){
    float4 v = ((const float4*)in)[i];
    ushort4 o;
    o.x = f2bf(v.x); o.y = f2bf(v.y); o.z = f2bf(v.z); o.w = f2bf(v.w);
    ((ushort4*)out)[i] = o;
  }
}

__device__ __forceinline__ void gl_lds16(const void* g, void* l){
  __builtin_amdgcn_global_load_lds(
      (const __attribute__((address_space(1))) unsigned int*)g,
      (__attribute__((address_space(3))) unsigned int*)l,
      16, 0, 0);
}

// C[M,N] = A[M,K] * B[N,K]^T ; A,B bf16 row-major; OUT = bf16(u16) or f32.
template<typename OUT>
__global__ __launch_bounds__(256) void gemm_bt(const u16* __restrict__ A,
                                               const u16* __restrict__ B,
                                               OUT* __restrict__ C,
                                               int M, int N, int K){
  __shared__ __align__(16) u16 lA[2][128*32];
  __shared__ __align__(16) u16 lB[2][128*32];
  const int tid  = threadIdx.x;
  const int lane = tid & 63;
  const int r16  = lane & 15;
  const int g4   = lane >> 4;
  const int wave = tid >> 6;
  const int wr = (wave >> 1) * 64, wc = (wave & 1) * 64;

  // bijective XCD swizzle (nwg % 8 == 0 for both GEMMs); contiguous wg range
  // within an XCD walks M-tiles at fixed N-panel ranges -> B-panel L2 reuse
  const int nwg = gridDim.x * gridDim.y;
  const int idl = blockIdx.y * gridDim.x + blockIdx.x;
  const int wg  = (idl & 7) * (nwg >> 3) + (idl >> 3);
  const int bx  = wg / gridDim.y, by = wg % gridDim.y;
  const int m0 = by * 128, n0 = bx * 128;

  const int srow = tid >> 2;          // 0..63
  const int scol = (tid & 3) << 3;    // 0,8,16,24

  f32x4 acc[4][4] = {};

  const int nk = K >> 5;
  int buf = 0;

  gl_lds16(&A[(size_t)(m0 + srow)*K + scol],      &lA[0][srow*32 + scol]);
  gl_lds16(&A[(size_t)(m0 + 64 + srow)*K + scol], &lA[0][(64+srow)*32 + scol]);
  gl_lds16(&B[(size_t)(n0 + srow)*K + scol],      &lB[0][srow*32 + scol]);
  gl_lds16(&B[(size_t)(n0 + 64 + srow)*K + scol], &lB[0][(64+srow)*32 + scol]);

  for (int kt = 0; kt < nk; ++kt){
    __syncthreads();
    if (kt + 1 < nk){
      const int k0 = (kt + 1) << 5;
      gl_lds16(&A[(size_t)(m0 + srow)*K + k0 + scol],      &lA[buf^1][srow*32 + scol]);
      gl_lds16(&A[(size_t)(m0 + 64 + srow)*K + k0 + scol], &lA[buf^1][(64+srow)*32 + scol]);
      gl_lds16(&B[(size_t)(n0 + srow)*K + k0 + scol],      &lB[buf^1][srow*32 + scol]);
      gl_lds16(&B[(size_t)(n0 + 64 + srow)*K + k0 + scol], &lB[buf^1][(64+srow)*32 + scol]);
    }
    short8 af[4], bfv[4];
    #pragma unroll
    for (int i=0;i<4;i++)
      af[i] = *(const short8*)&lA[buf][(wr + i*16 + r16)*32 + g4*8];
    #pragma unroll
    for (int j=0;j<4;j++)
      bfv[j] = *(const short8*)&lB[buf][(wc + j*16 + r16)*32 + g4*8];
    #pragma unroll
    for (int i=0;i<4;i++)
      #pragma unroll
      for (int j=0;j<4;j++)
        acc[i][j] = __builtin_amdgcn_mfma_f32_16x16x32_bf16(af[i], bfv[j], acc[i][j], 0,0,0);
    buf ^= 1;
  }

  #pragma unroll
  for (int i=0;i<4;i++){
    const int row = m0 + wr + i*16 + g4*4;
    #pragma unroll
    for (int j=0;j<4;j++){
      const int col = n0 + wc + j*16 + r16;
      #pragma unroll
      for (int r=0;r<4;r++){
        float v = acc[i][j][r];
        if constexpr (sizeof(OUT)==2) C[(size_t)(row+r)*N + col] = (OUT)f2bf(v);
        else                          C[(size_t)(row+r)*N + col] = (OUT)v;
      }
    }
  }
}

// Flash attention: 1D grid of B*NH*T/64=1024 blocks; 4 waves x 16 q-rows.
// Block remap: XCD x owns bh in [4x,4x+4) (K/V set 4MB = one L2); the 4 blocks
// sharing a CU slot (ids id, id+256, id+512, id+768) get qt weights summing
// to a constant 66 tiles -> balanced critical path.
__global__ __launch_bounds__(256) void attn_kernel(const u16* __restrict__ qkv,
                                                   u16* __restrict__ y){
  __shared__ __align__(16) u16 Kl[64*128];     // [kv][d], XOR-swizzled
  __shared__ __align__(16) u16 Vt[128*64];     // [d][kv], XOR-swizzled
  __shared__ __align__(16) u16 Pl[4][16*64];   // per-wave P, XOR-swizzled

  const int tid = threadIdx.x, lane = tid & 63, wave = tid >> 6;
  const int r16 = lane & 15, g4 = lane >> 4;

  const int id = blockIdx.x;            // 0..1023
  const int xk = id & 7,  kk = id >> 3; // xcd slot, 0..127
  const int bh = 4*xk + (kk & 3);
  const int v5 = kk >> 2;               // 0..31, cycles per CU-slot at stride 256
  const int a5 = v5 & 7, b5 = v5 >> 3;
  const int qt = (b5 & 1) ? (31 - (4*a5 + (b5 - 1))) : (4*a5 + b5);

  const int b = bh >> 4, h = bh & 15;
  const size_t base = (size_t)b * T_SEQ * QKV_LD;
  const int qcol = h*128, kcol = 2048 + h*128, vcol = 4096 + h*128;
  const float scale = 0.08838834764831845f;  // 1/sqrt(128)

  short8 qf[4];
  {
    const u16* qp = qkv + base + (size_t)(qt*64 + wave*16 + r16)*QKV_LD + qcol;
    #pragma unroll
    for (int c=0;c<4;c++) qf[c] = *(const short8*)&qp[g4*8 + c*32];
  }

  float mrow[4], lrow[4];
  #pragma unroll
  for (int r=0;r<4;r++){ mrow[r] = -1e30f; lrow[r] = 0.f; }
  f32x4 o[8] = {};

  const int strow = tid >> 4;          // 0..15
  const int stcol = (tid & 15) << 3;   // 0..120

  for (int t = 0; t <= qt; ++t){
    __syncthreads();   // previous tile's LDS reads all drained
    const size_t krow0 = base + (size_t)t*64*QKV_LD;
    // ---- stage K tile [64][128], swizzled, b128 writes
    #pragma unroll
    for (int r=0;r<4;r++){
      const int row = r*16 + strow;
      short8 kk2 = *(const short8*)&qkv[krow0 + (size_t)row*QKV_LD + kcol + stcol];
      *(short8*)&Kl[row*128 + (stcol ^ ((row&7)<<3))] = kk2;
    }
    // ---- stage V transposed: lane owns kv=lane
    #pragma unroll
    for (int r=0;r<4;r++){
      const int d0 = wave*8 + r*32;
      short8 vv = *(const short8*)&qkv[krow0 + (size_t)lane*QKV_LD + vcol + d0];
      #pragma unroll
      for (int j=0;j<8;j++){
        const int d = d0 + j;
        Vt[d*64 + (lane ^ ((d&7)<<3))] = (u16)vv[j];
      }
    }
    __syncthreads();

    // ---- S = Q K^T (16q x 64kv per wave)
    float smat[4][4];
    #pragma unroll
    for (int cc=0;cc<4;cc++){
      const int krow = cc*16 + r16;
      const int sw = (krow & 7) << 3;
      f32x4 sv = {0.f,0.f,0.f,0.f};
      #pragma unroll
      for (int dc=0;dc<4;dc++){
        short8 kf = *(const short8*)&Kl[krow*128 + ((g4*8 + dc*32) ^ sw)];
        sv = __builtin_amdgcn_mfma_f32_16x16x32_bf16(qf[dc], kf, sv, 0,0,0);
      }
      #pragma unroll
      for (int rr=0;rr<4;rr++) smat[cc][rr] = sv[rr] * scale;
    }
    if (t == qt){  // diagonal tile: causal mask (uniform branch)
      #pragma unroll
      for (int cc=0;cc<4;cc++){
        const int kvi = cc*16 + r16;
        #pragma unroll
        for (int rr=0;rr<4;rr++){
          const int qi = wave*16 + g4*4 + rr;
          if (kvi > qi) smat[cc][rr] = -1e30f;
        }
      }
    }

    // ---- online softmax (rows on 16-lane groups)
    float corr[4];
    #pragma unroll
    for (int rr=0;rr<4;rr++){
      float pm = fmaxf(fmaxf(smat[0][rr], smat[1][rr]), fmaxf(smat[2][rr], smat[3][rr]));
      #pragma unroll
      for (int off=1; off<16; off<<=1) pm = fmaxf(pm, __shfl_xor(pm, off, 64));
      const float mnew = fmaxf(mrow[rr], pm);
      corr[rr] = __expf(mrow[rr] - mnew);
      float s0 = 0.f;
      #pragma unroll
      for (int cc=0;cc<4;cc++){
        const float p = __expf(smat[cc][rr] - mnew);
        smat[cc][rr] = p;
        s0 += p;
      }
      #pragma unroll
      for (int off=1; off<16; off<<=1) s0 += __shfl_xor(s0, off, 64);
      lrow[rr] = lrow[rr]*corr[rr] + s0;
      mrow[rr] = mnew;
    }
    #pragma unroll
    for (int n=0;n<8;n++)
      #pragma unroll
      for (int rr=0;rr<4;rr++)
        o[n][rr] *= corr[rr];

    // ---- P -> LDS (bf16), then PV
    #pragma unroll
    for (int cc=0;cc<4;cc++)
      #pragma unroll
      for (int rr=0;rr<4;rr++){
        const int qr = g4*4 + rr;
        Pl[wave][qr*64 + ((cc*16 + r16) ^ ((qr&7)<<3))] = f2bf(smat[cc][rr]);
      }
    asm volatile("s_waitcnt lgkmcnt(0)" ::: "memory");

    short8 pf0 = *(const short8*)&Pl[wave][r16*64 + ((g4*8)      ^ ((r16&7)<<3))];
    short8 pf1 = *(const short8*)&Pl[wave][r16*64 + ((g4*8 + 32) ^ ((r16&7)<<3))];
    #pragma unroll
    for (int n=0;n<8;n++){
      const int vr = n*16 + r16;
      const int sw = (vr & 7) << 3;
      short8 vf0 = *(const short8*)&Vt[vr*64 + ((g4*8)      ^ sw)];
      short8 vf1 = *(const short8*)&Vt[vr*64 + ((g4*8 + 32) ^ sw)];
      o[n] = __builtin_amdgcn_mfma_f32_16x16x32_bf16(pf0, vf0, o[n], 0,0,0);
      o[n] = __builtin_amdgcn_mfma_f32_16x16x32_bf16(pf1, vf1, o[n], 0,0,0);
    }
  }

  const size_t yr0 = (size_t)(b*T_SEQ + qt*64 + wave*16 + g4*4) * C_DIM + h*128;
  #pragma unroll
  for (int n=0;n<8;n++)
    #pragma unroll
    for (int rr=0;rr<4;rr++){
      const float v = o[n][rr] / lrow[rr];
      y[yr0 + (size_t)rr*C_DIM + n*16 + r16] = f2bf(v);
    }
}

extern "C" void kernel_launch(void* const* d_in, const int* in_sizes, int n_in,
                              void* d_out, int out_size, void* d_ws, size_t ws_size,
                              hipStream_t stream){
  const float* x  = (const float*)d_in[0];
  const float* wa = (const float*)d_in[1];
  const float* wp = (const float*)d_in[2];
  float* out = (float*)d_out;

  u16* ws  = (u16*)d_ws;
  u16* xb  = ws;                 //  8388608 elems (x bf16) — reused as yb later
  u16* wab = xb  + 8388608;      // 12582912 elems (w_attn bf16)
  u16* wpb = wab + 12582912;     //  4194304 elems (w_proj bf16)
  u16* qkv = wpb + 4194304;      // 25165824 elems (qkv bf16)
  u16* yb  = xb;                 // alias: x no longer needed after GEMM1

  hipLaunchKernelGGL(cvt_kernel, dim3(1024), dim3(256), 0, stream, x,  xb,  8388608/4);
  hipLaunchKernelGGL(cvt_kernel, dim3(1024), dim3(256), 0, stream, wa, wab, 12582912/4);
  hipLaunchKernelGGL(cvt_kernel, dim3(1024), dim3(256), 0, stream, wp, wpb, 4194304/4);

  hipLaunchKernelGGL((gemm_bt<u16>),   dim3(48,32), dim3(256), 0, stream,
                     xb, wab, qkv, 4096, 6144, 2048);
  hipLaunchKernelGGL(attn_kernel,      dim3(1024), dim3(256), 0, stream, qkv, yb);
  hipLaunchKernelGGL((gemm_bt<float>), dim3(16,32), dim3(256), 0, stream,
                     yb, wpb, out, 4096, 2048, 2048);
}

// Round 4
// 321.618 us; speedup vs baseline: 1.2113x; 1.0101x over previous
//
#include <hip/hip_runtime.h>

typedef __attribute__((ext_vector_type(8))) short short8;
typedef __attribute__((ext_vector_type(4))) float f32x4;
typedef unsigned short u16;

#define T_SEQ 2048
#define C_DIM 2048
#define QKV_LD 6144

static __device__ __forceinline__ u16 f2bf(float f){
  unsigned u = __float_as_uint(f);
  u = (u + 0x7fffu + ((u >> 16) & 1u)) >> 16;
  return (u16)u;
}

__global__ void cvt_kernel(const float* __restrict__ in, u16* __restrict__ out, int n4){
  int idx = blockIdx.x * blockDim.x + threadIdx.x;
  int stride = gridDim.x * blockDim.x;
  for (int i = idx; i < n4; i += stride){
    float4 v = ((const float4*)in)[i];
    ushort4 o;
    o.x = f2bf(v.x); o.y = f2bf(v.y); o.z = f2bf(v.z); o.w = f2bf(v.w);
    ((ushort4*)out)[i] = o;
  }
}

__device__ __forceinline__ void gl_lds16(const void* g, void* l){
  __builtin_amdgcn_global_load_lds(
      (const __attribute__((address_space(1))) unsigned int*)g,
      (__attribute__((address_space(3))) unsigned int*)l,
      16, 0, 0);
}

// C[M,N] = A[M,K] * B[N,K]^T ; A,B bf16 row-major; OUT = bf16(u16) or f32.
template<typename OUT>
__global__ __launch_bounds__(256) void gemm_bt(const u16* __restrict__ A,
                                               const u16* __restrict__ B,
                                               OUT* __restrict__ C,
                                               int M, int N, int K){
  __shared__ __align__(16) u16 lA[2][128*32];
  __shared__ __align__(16) u16 lB[2][128*32];
  const int tid  = threadIdx.x;
  const int lane = tid & 63;
  const int r16  = lane & 15;
  const int g4   = lane >> 4;
  const int wave = tid >> 6;
  const int wr = (wave >> 1) * 64, wc = (wave & 1) * 64;

  const int nwg = gridDim.x * gridDim.y;
  const int idl = blockIdx.y * gridDim.x + blockIdx.x;
  const int wg  = (idl & 7) * (nwg >> 3) + (idl >> 3);
  const int bx  = wg / gridDim.y, by = wg % gridDim.y;
  const int m0 = by * 128, n0 = bx * 128;

  const int srow = tid >> 2;          // 0..63
  const int scol = (tid & 3) << 3;    // 0,8,16,24

  f32x4 acc[4][4] = {};

  const int nk = K >> 5;
  int buf = 0;

  gl_lds16(&A[(size_t)(m0 + srow)*K + scol],      &lA[0][srow*32 + scol]);
  gl_lds16(&A[(size_t)(m0 + 64 + srow)*K + scol], &lA[0][(64+srow)*32 + scol]);
  gl_lds16(&B[(size_t)(n0 + srow)*K + scol],      &lB[0][srow*32 + scol]);
  gl_lds16(&B[(size_t)(n0 + 64 + srow)*K + scol], &lB[0][(64+srow)*32 + scol]);

  for (int kt = 0; kt < nk; ++kt){
    __syncthreads();
    if (kt + 1 < nk){
      const int k0 = (kt + 1) << 5;
      gl_lds16(&A[(size_t)(m0 + srow)*K + k0 + scol],      &lA[buf^1][srow*32 + scol]);
      gl_lds16(&A[(size_t)(m0 + 64 + srow)*K + k0 + scol], &lA[buf^1][(64+srow)*32 + scol]);
      gl_lds16(&B[(size_t)(n0 + srow)*K + k0 + scol],      &lB[buf^1][srow*32 + scol]);
      gl_lds16(&B[(size_t)(n0 + 64 + srow)*K + k0 + scol], &lB[buf^1][(64+srow)*32 + scol]);
    }
    short8 af[4], bfv[4];
    #pragma unroll
    for (int i=0;i<4;i++)
      af[i] = *(const short8*)&lA[buf][(wr + i*16 + r16)*32 + g4*8];
    #pragma unroll
    for (int j=0;j<4;j++)
      bfv[j] = *(const short8*)&lB[buf][(wc + j*16 + r16)*32 + g4*8];
    #pragma unroll
    for (int i=0;i<4;i++)
      #pragma unroll
      for (int j=0;j<4;j++)
        acc[i][j] = __builtin_amdgcn_mfma_f32_16x16x32_bf16(af[i], bfv[j], acc[i][j], 0,0,0);
    buf ^= 1;
  }

  #pragma unroll
  for (int i=0;i<4;i++){
    const int row = m0 + wr + i*16 + g4*4;
    #pragma unroll
    for (int j=0;j<4;j++){
      const int col = n0 + wc + j*16 + r16;
      #pragma unroll
      for (int r=0;r<4;r++){
        float v = acc[i][j][r];
        if constexpr (sizeof(OUT)==2) C[(size_t)(row+r)*N + col] = (OUT)f2bf(v);
        else                          C[(size_t)(row+r)*N + col] = (OUT)v;
      }
    }
  }
}

// Flash attention, QBLK=128: grid of B*NH*(T/128)=512 blocks; 4 waves, each
// owns 32 q-rows (2 row-fragments). KVBLK=64.
// Remap: XCD x owns bh in [4x,4x+4); co-slot blocks (id, id+256) share bh and
// get qt pair (v, 15-v): per-slot kv-tile weight (2qt+2) sums to constant 34.
__global__ __launch_bounds__(256) void attn_kernel(const u16* __restrict__ qkv,
                                                   u16* __restrict__ y){
  __shared__ __align__(16) u16 Kl[64*128];     // [kv][d], XOR-swizzled
  __shared__ __align__(16) u16 Vt[128*64];     // [d][kv], XOR-swizzled
  __shared__ __align__(16) u16 Pl[4][32*64];   // per-wave P [32 q][64 kv], swizzled

  const int tid = threadIdx.x, lane = tid & 63, wave = tid >> 6;
  const int r16 = lane & 15, g4 = lane >> 4;

  const int id = blockIdx.x;            // 0..511
  const int xk = id & 7,  kk = id >> 3; // xcd, 0..63
  const int bh = 4*xk + (kk & 3);
  const int v5 = kk >> 2;               // 0..15
  const int qt = (v5 < 8) ? v5 : (23 - v5);   // pairs (v,15-v) share a CU slot

  const int b = bh >> 4, h = bh & 15;
  const size_t base = (size_t)b * T_SEQ * QKV_LD;
  const int qcol = h*128, kcol = 2048 + h*128, vcol = 4096 + h*128;
  const float scale = 0.08838834764831845f;  // 1/sqrt(128)

  short8 qf[2][4];
  #pragma unroll
  for (int i=0;i<2;i++){
    const u16* qp = qkv + base + (size_t)(qt*128 + wave*32 + i*16 + r16)*QKV_LD + qcol;
    #pragma unroll
    for (int c=0;c<4;c++) qf[i][c] = *(const short8*)&qp[g4*8 + c*32];
  }

  float mrow[2][4], lrow[2][4];
  #pragma unroll
  for (int i=0;i<2;i++)
    #pragma unroll
    for (int r=0;r<4;r++){ mrow[i][r] = -1e30f; lrow[i][r] = 0.f; }
  f32x4 o[2][8] = {};

  const int strow = tid >> 4;          // 0..15
  const int stcol = (tid & 15) << 3;   // 0..120

  const int nt = 2*qt + 2;
  for (int t = 0; t < nt; ++t){
    __syncthreads();
    const size_t krow0 = base + (size_t)t*64*QKV_LD;
    // ---- stage K tile [64][128], swizzled, b128 writes
    #pragma unroll
    for (int r=0;r<4;r++){
      const int row = r*16 + strow;
      short8 kk2 = *(const short8*)&qkv[krow0 + (size_t)row*QKV_LD + kcol + stcol];
      *(short8*)&Kl[row*128 + (stcol ^ ((row&7)<<3))] = kk2;
    }
    // ---- stage V transposed: lane owns kv=lane
    #pragma unroll
    for (int r=0;r<4;r++){
      const int d0 = wave*8 + r*32;
      short8 vv = *(const short8*)&qkv[krow0 + (size_t)lane*QKV_LD + vcol + d0];
      #pragma unroll
      for (int j=0;j<8;j++){
        const int d = d0 + j;
        Vt[d*64 + (lane ^ ((d&7)<<3))] = (u16)vv[j];
      }
    }
    __syncthreads();

    // ---- S = Q K^T : per wave 32q x 64kv
    float smat[2][4][4];
    #pragma unroll
    for (int cc=0;cc<4;cc++){
      const int krow = cc*16 + r16;
      const int sw = (krow & 7) << 3;
      short8 kf[4];
      #pragma unroll
      for (int dc=0;dc<4;dc++)
        kf[dc] = *(const short8*)&Kl[krow*128 + ((g4*8 + dc*32) ^ sw)];
      #pragma unroll
      for (int i=0;i<2;i++){
        f32x4 sv = {0.f,0.f,0.f,0.f};
        #pragma unroll
        for (int dc=0;dc<4;dc++)
          sv = __builtin_amdgcn_mfma_f32_16x16x32_bf16(qf[i][dc], kf[dc], sv, 0,0,0);
        #pragma unroll
        for (int rr=0;rr<4;rr++) smat[i][cc][rr] = sv[rr] * scale;
      }
    }
    if (t >= 2*qt){  // diagonal region (uniform branch)
      #pragma unroll
      for (int cc=0;cc<4;cc++){
        const int kvl = (t - 2*qt)*64 + cc*16 + r16;
        #pragma unroll
        for (int i=0;i<2;i++)
          #pragma unroll
          for (int rr=0;rr<4;rr++){
            const int qi = wave*32 + i*16 + g4*4 + rr;
            if (kvl > qi) smat[i][cc][rr] = -1e30f;
          }
      }
    }

    // ---- online softmax (rows on 16-lane groups)
    float corr[2][4];
    #pragma unroll
    for (int i=0;i<2;i++)
      #pragma unroll
      for (int rr=0;rr<4;rr++){
        float pm = fmaxf(fmaxf(smat[i][0][rr], smat[i][1][rr]),
                         fmaxf(smat[i][2][rr], smat[i][3][rr]));
        #pragma unroll
        for (int off=1; off<16; off<<=1) pm = fmaxf(pm, __shfl_xor(pm, off, 64));
        const float mnew = fmaxf(mrow[i][rr], pm);
        corr[i][rr] = __expf(mrow[i][rr] - mnew);
        float s0 = 0.f;
        #pragma unroll
        for (int cc=0;cc<4;cc++){
          const float p = __expf(smat[i][cc][rr] - mnew);
          smat[i][cc][rr] = p;
          s0 += p;
        }
        #pragma unroll
        for (int off=1; off<16; off<<=1) s0 += __shfl_xor(s0, off, 64);
        lrow[i][rr] = lrow[i][rr]*corr[i][rr] + s0;
        mrow[i][rr] = mnew;
      }
    #pragma unroll
    for (int i=0;i<2;i++)
      #pragma unroll
      for (int n=0;n<8;n++)
        #pragma unroll
        for (int rr=0;rr<4;rr++)
          o[i][n][rr] *= corr[i][rr];

    // ---- P -> LDS (bf16), rows 0..31 per wave
    #pragma unroll
    for (int i=0;i<2;i++)
      #pragma unroll
      for (int cc=0;cc<4;cc++)
        #pragma unroll
        for (int rr=0;rr<4;rr++){
          const int qr = i*16 + g4*4 + rr;
          Pl[wave][qr*64 + ((cc*16 + r16) ^ ((qr&7)<<3))] = f2bf(smat[i][cc][rr]);
        }
    asm volatile("s_waitcnt lgkmcnt(0)" ::: "memory");

    short8 pf[2][2];
    #pragma unroll
    for (int i=0;i<2;i++){
      const int qr = i*16 + r16;
      const int sw = (qr & 7) << 3;   // == (r16&7)<<3
      pf[i][0] = *(const short8*)&Pl[wave][qr*64 + ((g4*8)      ^ sw)];
      pf[i][1] = *(const short8*)&Pl[wave][qr*64 + ((g4*8 + 32) ^ sw)];
    }
    #pragma unroll
    for (int n=0;n<8;n++){
      const int vr = n*16 + r16;
      const int sw = (vr & 7) << 3;
      short8 vf0 = *(const short8*)&Vt[vr*64 + ((g4*8)      ^ sw)];
      short8 vf1 = *(const short8*)&Vt[vr*64 + ((g4*8 + 32) ^ sw)];
      #pragma unroll
      for (int i=0;i<2;i++){
        o[i][n] = __builtin_amdgcn_mfma_f32_16x16x32_bf16(pf[i][0], vf0, o[i][n], 0,0,0);
        o[i][n] = __builtin_amdgcn_mfma_f32_16x16x32_bf16(pf[i][1], vf1, o[i][n], 0,0,0);
      }
    }
  }

  #pragma unroll
  for (int i=0;i<2;i++){
    const size_t yr0 = (size_t)(b*T_SEQ + qt*128 + wave*32 + i*16 + g4*4) * C_DIM + h*128;
    #pragma unroll
    for (int n=0;n<8;n++)
      #pragma unroll
      for (int rr=0;rr<4;rr++){
        const float v = o[i][n][rr] / lrow[i][rr];
        y[yr0 + (size_t)rr*C_DIM + n*16 + r16] = f2bf(v);
      }
  }
}

extern "C" void kernel_launch(void* const* d_in, const int* in_sizes, int n_in,
                              void* d_out, int out_size, void* d_ws, size_t ws_size,
                              hipStream_t stream){
  const float* x  = (const float*)d_in[0];
  const float* wa = (const float*)d_in[1];
  const float* wp = (const float*)d_in[2];
  float* out = (float*)d_out;

  u16* ws  = (u16*)d_ws;
  u16* xb  = ws;                 //  8388608 elems (x bf16) — reused as yb later
  u16* wab = xb  + 8388608;      // 12582912 elems (w_attn bf16)
  u16* wpb = wab + 12582912;     //  4194304 elems (w_proj bf16)
  u16* qkv = wpb + 4194304;      // 25165824 elems (qkv bf16)
  u16* yb  = xb;                 // alias: x no longer needed after GEMM1

  hipLaunchKernelGGL(cvt_kernel, dim3(1024), dim3(256), 0, stream, x,  xb,  8388608/4);
  hipLaunchKernelGGL(cvt_kernel, dim3(1024), dim3(256), 0, stream, wa, wab, 12582912/4);
  hipLaunchKernelGGL(cvt_kernel, dim3(1024), dim3(256), 0, stream, wp, wpb, 4194304/4);

  hipLaunchKernelGGL((gemm_bt<u16>),   dim3(48,32), dim3(256), 0, stream,
                     xb, wab, qkv, 4096, 6144, 2048);
  hipLaunchKernelGGL(attn_kernel,      dim3(512),  dim3(256), 0, stream, qkv, yb);
  hipLaunchKernelGGL((gemm_bt<float>), dim3(16,32), dim3(256), 0, stream,
                     yb, wpb, out, 4096, 2048, 2048);
}

// Round 5
// 316.342 us; speedup vs baseline: 1.2315x; 1.0167x over previous
//
#include <hip/hip_runtime.h>

typedef __attribute__((ext_vector_type(8))) short short8;
typedef __attribute__((ext_vector_type(4))) float f32x4;
typedef unsigned short u16;

#define T_SEQ 2048
#define C_DIM 2048

static __device__ __forceinline__ u16 f2bf(float f){
  unsigned u = __float_as_uint(f);
  u = (u + 0x7fffu + ((u >> 16) & 1u)) >> 16;
  return (u16)u;
}

__global__ void cvt_kernel(const float* __restrict__ in, u16* __restrict__ out, int n4){
  int idx = blockIdx.x * blockDim.x + threadIdx.x;
  int stride = gridDim.x * blockDim.x;
  for (int i = idx; i < n4; i += stride){
    float4 v = ((const float4*)in)[i];
    ushort4 o;
    o.x = f2bf(v.x); o.y = f2bf(v.y); o.z = f2bf(v.z); o.w = f2bf(v.w);
    ((ushort4*)out)[i] = o;
  }
}

__device__ __forceinline__ void gl_lds16(const void* g, void* l){
  __builtin_amdgcn_global_load_lds(
      (const __attribute__((address_space(1))) unsigned int*)g,
      (__attribute__((address_space(3))) unsigned int*)l,
      16, 0, 0);
}

// C = A[M,K] * B[N,K]^T, bf16 in, tiles 128x128.
// MODE 0: plain write to C[M,N] (LD=N), OUT type.
// MODE 1: qkv-split: cols<4096 -> C (=qk, LD 4096); cols>=4096 (V third) ->
//         VT[b][h][d][t] (b=row>>11, t=row&2047, h=(col-4096)>>7, d=(col-4096)&127)
template<int MODE, typename OUT>
__global__ __launch_bounds__(256) void gemm_bt(const u16* __restrict__ A,
                                               const u16* __restrict__ B,
                                               OUT* __restrict__ C,
                                               u16* __restrict__ VT,
                                               int M, int N, int K){
  __shared__ __align__(16) u16 lA[2][128*32];
  __shared__ __align__(16) u16 lB[2][128*32];
  const int tid  = threadIdx.x;
  const int lane = tid & 63;
  const int r16  = lane & 15;
  const int g4   = lane >> 4;
  const int wave = tid >> 6;
  const int wr = (wave >> 1) * 64, wc = (wave & 1) * 64;

  const int nwg = gridDim.x * gridDim.y;
  const int idl = blockIdx.y * gridDim.x + blockIdx.x;
  const int wg  = (idl & 7) * (nwg >> 3) + (idl >> 3);
  const int bx  = wg / gridDim.y, by = wg % gridDim.y;
  const int m0 = by * 128, n0 = bx * 128;

  const int srow = tid >> 2;          // 0..63
  const int scol = (tid & 3) << 3;    // 0,8,16,24

  f32x4 acc[4][4] = {};

  const int nk = K >> 5;
  int buf = 0;

  gl_lds16(&A[(size_t)(m0 + srow)*K + scol],      &lA[0][srow*32 + scol]);
  gl_lds16(&A[(size_t)(m0 + 64 + srow)*K + scol], &lA[0][(64+srow)*32 + scol]);
  gl_lds16(&B[(size_t)(n0 + srow)*K + scol],      &lB[0][srow*32 + scol]);
  gl_lds16(&B[(size_t)(n0 + 64 + srow)*K + scol], &lB[0][(64+srow)*32 + scol]);

  for (int kt = 0; kt < nk; ++kt){
    __syncthreads();
    if (kt + 1 < nk){
      const int k0 = (kt + 1) << 5;
      gl_lds16(&A[(size_t)(m0 + srow)*K + k0 + scol],      &lA[buf^1][srow*32 + scol]);
      gl_lds16(&A[(size_t)(m0 + 64 + srow)*K + k0 + scol], &lA[buf^1][(64+srow)*32 + scol]);
      gl_lds16(&B[(size_t)(n0 + srow)*K + k0 + scol],      &lB[buf^1][srow*32 + scol]);
      gl_lds16(&B[(size_t)(n0 + 64 + srow)*K + k0 + scol], &lB[buf^1][(64+srow)*32 + scol]);
    }
    short8 af[4], bfv[4];
    #pragma unroll
    for (int i=0;i<4;i++)
      af[i] = *(const short8*)&lA[buf][(wr + i*16 + r16)*32 + g4*8];
    #pragma unroll
    for (int j=0;j<4;j++)
      bfv[j] = *(const short8*)&lB[buf][(wc + j*16 + r16)*32 + g4*8];
    #pragma unroll
    for (int i=0;i<4;i++)
      #pragma unroll
      for (int j=0;j<4;j++)
        acc[i][j] = __builtin_amdgcn_mfma_f32_16x16x32_bf16(af[i], bfv[j], acc[i][j], 0,0,0);
    buf ^= 1;
  }

  if (MODE == 1 && n0 >= 4096){
    // V third -> VT[b][h][d][t], 8B packed store per (i,j)
    #pragma unroll
    for (int i=0;i<4;i++){
      const int m = m0 + wr + i*16 + g4*4;
      const int bb = m >> 11, t = m & 2047;
      #pragma unroll
      for (int j=0;j<4;j++){
        const int cv = n0 + wc + j*16 + r16 - 4096;
        const int h = cv >> 7, dl = cv & 127;
        ushort4 pack;
        pack.x = f2bf(acc[i][j][0]); pack.y = f2bf(acc[i][j][1]);
        pack.z = f2bf(acc[i][j][2]); pack.w = f2bf(acc[i][j][3]);
        *(ushort4*)&VT[(size_t)((bb<<4) + h)*262144 + (size_t)dl*2048 + t] = pack;
      }
    }
  } else {
    const int ldc = (MODE == 1) ? 4096 : N;
    #pragma unroll
    for (int i=0;i<4;i++){
      const int row = m0 + wr + i*16 + g4*4;
      #pragma unroll
      for (int j=0;j<4;j++){
        const int col = n0 + wc + j*16 + r16;
        #pragma unroll
        for (int r=0;r<4;r++){
          float v = acc[i][j][r];
          if constexpr (sizeof(OUT)==2) C[(size_t)(row+r)*ldc + col] = (OUT)f2bf(v);
          else                          C[(size_t)(row+r)*ldc + col] = (OUT)v;
        }
      }
    }
  }
}

// Flash attention, QBLK=128, KVBLK=64, 2-phase gl_lds pipeline.
// qk: [B*T][4096] (Q cols 0..2047, K cols 2048..4095), vt: [B*16+h][128][2048].
// Remap: XCD x owns bh in [4x,4x+4); co-slot blocks (id, id+256) get qt pair
// (v, 15-v): per-slot kv-tile weight sums to constant 34.
__global__ __launch_bounds__(256) void attn_kernel(const u16* __restrict__ qk,
                                                   const u16* __restrict__ vt,
                                                   u16* __restrict__ y){
  __shared__ __align__(16) u16 Kl[2][64*128];  // [kv][d], XOR-swizzled content
  __shared__ __align__(16) u16 Vl[2][128*64];  // [d][kv], XOR-swizzled content
  __shared__ __align__(16) u16 Pl[4][32*64];   // per-wave P, XOR-swizzled

  const int tid = threadIdx.x, lane = tid & 63, wave = tid >> 6;
  const int r16 = lane & 15, g4 = lane >> 4;

  const int id = blockIdx.x;            // 0..511
  const int xk = id & 7,  kk = id >> 3; // xcd, 0..63
  const int bh = 4*xk + (kk & 3);
  const int v5 = kk >> 2;               // 0..15
  const int qt = (v5 < 8) ? v5 : (23 - v5);

  const int b = bh >> 4, h = bh & 15;
  const int qcol = h*128, kcol = 2048 + h*128;
  const u16* vhead = vt + (size_t)bh * 262144;
  const float scale = 0.08838834764831845f;  // 1/sqrt(128)

  short8 qf[2][4];
  #pragma unroll
  for (int i=0;i<2;i++){
    const u16* qp = qk + (size_t)(b*T_SEQ + qt*128 + wave*32 + i*16 + r16)*4096 + qcol;
    #pragma unroll
    for (int c=0;c<4;c++) qf[i][c] = *(const short8*)&qp[g4*8 + c*32];
  }

  float mrow[2][4], lrow[2][4];
  #pragma unroll
  for (int i=0;i<2;i++)
    #pragma unroll
    for (int r=0;r<4;r++){ mrow[i][r] = -1e30f; lrow[i][r] = 0.f; }
  f32x4 o[2][8] = {};

  const int nt = 2*qt + 2;

  // ---- staging macro-equivalent (K and V^T tiles, pre-swizzled source)
  auto stage = [&](int sbuf, int t){
    const size_t kbase = (size_t)(b*T_SEQ + t*64)*4096 + kcol;
    #pragma unroll
    for (int c=0;c<4;c++){
      const int row0 = wave*16 + c*4;       // wave-uniform
      const int row  = row0 + g4;
      gl_lds16(&qk[kbase + (size_t)row*4096 + ((r16*8) ^ ((row&7)<<3))],
               &Kl[sbuf][row0*128]);
    }
    const int t0 = t*64;
    #pragma unroll
    for (int c=0;c<4;c++){
      const int idx = wave*4 + c;           // 0..15, wave-uniform
      const int d   = idx*8 + (lane>>3);
      const int j8  = (lane&7)*8;
      gl_lds16(&vhead[(size_t)d*2048 + t0 + (j8 ^ ((d&7)<<3))],
               &Vl[sbuf][idx*512]);
    }
  };

  stage(0, 0);
  int cur = 0;

  for (int t = 0; t < nt; ++t){
    __syncthreads();           // drains vmcnt -> buf[cur] ready; prev reads done
    if (t + 1 < nt) stage(cur^1, t+1);

    // ---- S = Q K^T : per wave 32q x 64kv
    float smat[2][4][4];
    #pragma unroll
    for (int cc=0;cc<4;cc++){
      const int krow = cc*16 + r16;
      const int sw = (krow & 7) << 3;
      short8 kf[4];
      #pragma unroll
      for (int dc=0;dc<4;dc++)
        kf[dc] = *(const short8*)&Kl[cur][krow*128 + ((g4*8 + dc*32) ^ sw)];
      #pragma unroll
      for (int i=0;i<2;i++){
        f32x4 sv = {0.f,0.f,0.f,0.f};
        #pragma unroll
        for (int dc=0;dc<4;dc++)
          sv = __builtin_amdgcn_mfma_f32_16x16x32_bf16(qf[i][dc], kf[dc], sv, 0,0,0);
        #pragma unroll
        for (int rr=0;rr<4;rr++) smat[i][cc][rr] = sv[rr] * scale;
      }
    }
    if (t >= 2*qt){  // diagonal region (uniform branch)
      #pragma unroll
      for (int cc=0;cc<4;cc++){
        const int kvl = (t - 2*qt)*64 + cc*16 + r16;
        #pragma unroll
        for (int i=0;i<2;i++)
          #pragma unroll
          for (int rr=0;rr<4;rr++){
            const int qi = wave*32 + i*16 + g4*4 + rr;
            if (kvl > qi) smat[i][cc][rr] = -1e30f;
          }
      }
    }

    // ---- online softmax (rows on 16-lane groups)
    float corr[2][4];
    #pragma unroll
    for (int i=0;i<2;i++)
      #pragma unroll
      for (int rr=0;rr<4;rr++){
        float pm = fmaxf(fmaxf(smat[i][0][rr], smat[i][1][rr]),
                         fmaxf(smat[i][2][rr], smat[i][3][rr]));
        #pragma unroll
        for (int off=1; off<16; off<<=1) pm = fmaxf(pm, __shfl_xor(pm, off, 64));
        const float mnew = fmaxf(mrow[i][rr], pm);
        corr[i][rr] = __expf(mrow[i][rr] - mnew);
        float s0 = 0.f;
        #pragma unroll
        for (int cc=0;cc<4;cc++){
          const float p = __expf(smat[i][cc][rr] - mnew);
          smat[i][cc][rr] = p;
          s0 += p;
        }
        #pragma unroll
        for (int off=1; off<16; off<<=1) s0 += __shfl_xor(s0, off, 64);
        lrow[i][rr] = lrow[i][rr]*corr[i][rr] + s0;
        mrow[i][rr] = mnew;
      }
    #pragma unroll
    for (int i=0;i<2;i++)
      #pragma unroll
      for (int n=0;n<8;n++)
        #pragma unroll
        for (int rr=0;rr<4;rr++)
          o[i][n][rr] *= corr[i][rr];

    // ---- P -> LDS (bf16), wave-local
    #pragma unroll
    for (int i=0;i<2;i++)
      #pragma unroll
      for (int cc=0;cc<4;cc++)
        #pragma unroll
        for (int rr=0;rr<4;rr++){
          const int qr = i*16 + g4*4 + rr;
          Pl[wave][qr*64 + ((cc*16 + r16) ^ ((qr&7)<<3))] = f2bf(smat[i][cc][rr]);
        }
    asm volatile("s_waitcnt lgkmcnt(0)" ::: "memory");

    short8 pf[2][2];
    #pragma unroll
    for (int i=0;i<2;i++){
      const int qr = i*16 + r16;
      const int sw = (qr & 7) << 3;
      pf[i][0] = *(const short8*)&Pl[wave][qr*64 + ((g4*8)      ^ sw)];
      pf[i][1] = *(const short8*)&Pl[wave][qr*64 + ((g4*8 + 32) ^ sw)];
    }
    #pragma unroll
    for (int n=0;n<8;n++){
      const int vr = n*16 + r16;
      const int sw = (vr & 7) << 3;
      short8 vf0 = *(const short8*)&Vl[cur][vr*64 + ((g4*8)      ^ sw)];
      short8 vf1 = *(const short8*)&Vl[cur][vr*64 + ((g4*8 + 32) ^ sw)];
      #pragma unroll
      for (int i=0;i<2;i++){
        o[i][n] = __builtin_amdgcn_mfma_f32_16x16x32_bf16(pf[i][0], vf0, o[i][n], 0,0,0);
        o[i][n] = __builtin_amdgcn_mfma_f32_16x16x32_bf16(pf[i][1], vf1, o[i][n], 0,0,0);
      }
    }
    cur ^= 1;
  }

  #pragma unroll
  for (int i=0;i<2;i++){
    const size_t yr0 = (size_t)(b*T_SEQ + qt*128 + wave*32 + i*16 + g4*4) * C_DIM + h*128;
    #pragma unroll
    for (int n=0;n<8;n++)
      #pragma unroll
      for (int rr=0;rr<4;rr++){
        const float v = o[i][n][rr] / lrow[i][rr];
        y[yr0 + (size_t)rr*C_DIM + n*16 + r16] = f2bf(v);
      }
  }
}

extern "C" void kernel_launch(void* const* d_in, const int* in_sizes, int n_in,
                              void* d_out, int out_size, void* d_ws, size_t ws_size,
                              hipStream_t stream){
  const float* x  = (const float*)d_in[0];
  const float* wa = (const float*)d_in[1];
  const float* wp = (const float*)d_in[2];
  float* out = (float*)d_out;

  u16* ws  = (u16*)d_ws;
  u16* xb  = ws;                 //  8,388,608 elems (x bf16) — reused as yb later
  u16* wab = xb  + 8388608;      // 12,582,912 elems (w_attn bf16)
  u16* wpb = wab + 12582912;     //  4,194,304 elems (w_proj bf16)
  u16* qk  = wpb + 4194304;      // 16,777,216 elems ([4096][4096] Q|K)
  u16* vt  = qk  + 16777216;     //  8,388,608 elems ([32][128][2048] V^T)
  u16* yb  = xb;                 // alias: x dead after GEMM1

  hipLaunchKernelGGL(cvt_kernel, dim3(1024), dim3(256), 0, stream, x,  xb,  8388608/4);
  hipLaunchKernelGGL(cvt_kernel, dim3(1024), dim3(256), 0, stream, wa, wab, 12582912/4);
  hipLaunchKernelGGL(cvt_kernel, dim3(1024), dim3(256), 0, stream, wp, wpb, 4194304/4);

  // qkv projection with V-split epilogue
  hipLaunchKernelGGL((gemm_bt<1,u16>),   dim3(48,32), dim3(256), 0, stream,
                     xb, wab, qk, vt, 4096, 6144, 2048);
  hipLaunchKernelGGL(attn_kernel,        dim3(512),  dim3(256), 0, stream,
                     qk, vt, yb);
  hipLaunchKernelGGL((gemm_bt<0,float>), dim3(16,32), dim3(256), 0, stream,
                     yb, wpb, out, (u16*)nullptr, 4096, 2048, 2048);
}